// Round 1
// baseline (1122.552 us; speedup 1.0000x reference)
//
#include <hip/hip_runtime.h>
#include <hip/hip_bf16.h>
#include <math.h>

#define HDIM 128
#define BN_EPS 1e-5f

// ---- edge index fetch: handles int32 or int64 on-device layout ----
__device__ __forceinline__ int eget(const void* ei, long long pos, int is64) {
    return is64 ? (int)((const long long*)ei)[pos] : ((const int*)ei)[pos];
}

// Detect int64 vs int32 layout: when data is int64 (values < 2^31, nonneg),
// odd int32 words are all zero. When int32, odd words are random node ids.
__global__ void k_detect(const int* ei32, int* flag) {
    if (threadIdx.x == 0) {
        int nz = 0;
        for (int k = 0; k < 64; ++k) nz += (ei32[2 * k + 1] != 0);
        *flag = (nz < 8) ? 1 : 0;   // 1 => int64
    }
}

__global__ void k_fill(float* p, float v, long long n) {
    long long t = (long long)blockIdx.x * blockDim.x + threadIdx.x;
    if (t < n) p[t] = v;
}

__global__ void k_deg(const void* ei, const int* flag, float* deg, int E) {
    int e = blockIdx.x * blockDim.x + threadIdx.x;
    if (e < E) {
        int d = eget(ei, (long long)E + e, *flag);
        atomicAdd(&deg[d], 1.0f);
    }
}

__global__ void k_rsqrt_inplace(float* deg, int N) {
    int i = blockIdx.x * blockDim.x + threadIdx.x;
    if (i < N) deg[i] = rsqrtf(deg[i]);   // deg >= 1 always (self loops)
}

// aggx[i][k] = x[i][k] * dis[i]^2  (self-loop term), 6-wide
__global__ void k_init_aggx(const float* x, const float* dis, float* aggx, int N) {
    int t = blockIdx.x * blockDim.x + threadIdx.x;
    if (t < N * 6) {
        int i = t / 6;
        float d = dis[i];
        aggx[t] = x[t] * d * d;
    }
}

// scatter 6-wide input features along edges
__global__ void k_scat_x(const float* x, const void* ei, const int* flag,
                         const float* dis, float* aggx, int E) {
    int e = blockIdx.x * blockDim.x + threadIdx.x;
    if (e < E) {
        int is64 = *flag;
        int s = eget(ei, e, is64);
        int d = eget(ei, (long long)E + e, is64);
        float nrm = dis[s] * dis[d];
        #pragma unroll
        for (int k = 0; k < 6; ++k)
            atomicAdd(&aggx[d * 6 + k], x[s * 6 + k] * nrm);
    }
}

// out[i][j] = sum_k aggx[i][k] * W1[k][j] + b1[j]   (K=6)
__global__ void k_gemm6(const float* aggx, const float* W1, const float* b1,
                        float* out, int N) {
    __shared__ float w[6 * HDIM];
    __shared__ float bb[HDIM];
    for (int t = threadIdx.x; t < 6 * HDIM; t += blockDim.x) w[t] = W1[t];
    if (threadIdx.x < HDIM) bb[threadIdx.x] = b1[threadIdx.x];
    __syncthreads();
    int j = threadIdx.x & (HDIM - 1);
    int sub = threadIdx.x >> 7;               // 2 rows per 256-thread block
    for (int i = blockIdx.x * 2 + sub; i < N; i += gridDim.x * 2) {
        const float* r = &aggx[i * 6];
        float acc = bb[j];
        acc += r[0] * w[0 * HDIM + j];
        acc += r[1] * w[1 * HDIM + j];
        acc += r[2] * w[2 * HDIM + j];
        acc += r[3] * w[3 * HDIM + j];
        acc += r[4] * w[4 * HDIM + j];
        acc += r[5] * w[5 * HDIM + j];
        out[(long long)i * HDIM + j] = acc;
    }
}

// per-column sum and sum-of-squares -> S[0:128]=sum, S[128:256]=sumsq
__global__ void k_colsum(const float* h, int N, float* S) {
    int j = threadIdx.x & (HDIM - 1);
    int sub = threadIdx.x >> 7;
    float s1 = 0.f, s2 = 0.f;
    for (int i = blockIdx.x * 2 + sub; i < N; i += gridDim.x * 2) {
        float v = h[(long long)i * HDIM + j];
        s1 += v; s2 += v * v;
    }
    __shared__ float sh1[256], sh2[256];
    sh1[threadIdx.x] = s1; sh2[threadIdx.x] = s2;
    __syncthreads();
    if (threadIdx.x < HDIM) {
        s1 = sh1[threadIdx.x] + sh1[threadIdx.x + HDIM];
        s2 = sh2[threadIdx.x] + sh2[threadIdx.x + HDIM];
        atomicAdd(&S[j], s1);
        atomicAdd(&S[HDIM + j], s2);
    }
}

// P[0:128] = alpha = g*rsqrt(var+eps), P[128:256] = beta = be - mu*alpha
__global__ void k_bnparams(const float* S, const float* g, const float* be,
                           float invN, float* P) {
    int j = threadIdx.x;
    if (j < HDIM) {
        float mu = S[j] * invN;
        float var = S[HDIM + j] * invN - mu * mu;
        float a = g[j] * rsqrtf(var + BN_EPS);
        P[j] = a;
        P[HDIM + j] = be[j] - mu * a;
    }
}

// h = relu(alpha*h+beta) in place; optionally also write agg_init = h*dis^2
__global__ void k_bnrelu(float* h, const float* P, const float* dis,
                         float* agg_init, int N) {
    long long t = (long long)blockIdx.x * blockDim.x + threadIdx.x;
    if (t < (long long)N * HDIM) {
        int j = (int)(t & (HDIM - 1));
        int i = (int)(t >> 7);
        float v = h[t];
        v = fmaxf(P[j] * v + P[HDIM + j], 0.f);
        h[t] = v;
        if (agg_init) {
            float d = dis[i];
            agg_init[t] = v * d * d;
        }
    }
}

// scatter 128-wide rows along edges: agg[dst][j] += h[src][j]*norm
// block of 256 threads handles 2 edges (128 lanes each)
__global__ void k_scat_h(const float* hsrc, const void* ei, const int* flag,
                         const float* dis, float* agg, int E) {
    int e = blockIdx.x * 2 + (threadIdx.x >> 7);
    int j = threadIdx.x & (HDIM - 1);
    if (e < E) {
        int is64 = *flag;
        int s = eget(ei, e, is64);
        int d = eget(ei, (long long)E + e, is64);
        float nrm = dis[s] * dis[d];
        float v = hsrc[(long long)s * HDIM + j] * nrm;
        atomicAdd(&agg[(long long)d * HDIM + j], v);
    }
}

// out[i][j] = sum_k A[i][k]*W[k][j] + b[j]   (K=128), W staged in LDS
__global__ void k_gemm128(const float* A, const float* W, const float* b,
                          float* out, int N) {
    __shared__ float w[HDIM * HDIM];
    __shared__ float bb[HDIM];
    for (int t = threadIdx.x; t < HDIM * HDIM; t += blockDim.x) w[t] = W[t];
    if (threadIdx.x < HDIM) bb[threadIdx.x] = b[threadIdx.x];
    __syncthreads();
    int j = threadIdx.x & (HDIM - 1);
    int sub = threadIdx.x >> 7;
    for (int i = blockIdx.x * 2 + sub; i < N; i += gridDim.x * 2) {
        const float* r = &A[(long long)i * HDIM];
        float acc = bb[j];
        #pragma unroll 8
        for (int k = 0; k < HDIM; ++k)
            acc = fmaf(r[k], w[k * HDIM + j], acc);
        out[(long long)i * HDIM + j] = acc;
    }
}

// m3[i] = dot(h2[i], W3)  (128 -> 1); block handles 2 rows
__global__ void k_gemv(const float* A, const float* W3, float* m3, int N) {
    __shared__ float w[HDIM];
    __shared__ float part[4];
    if (threadIdx.x < HDIM) w[threadIdx.x] = W3[threadIdx.x];
    __syncthreads();
    int sub = threadIdx.x >> 7;
    int j = threadIdx.x & (HDIM - 1);
    int i = blockIdx.x * 2 + sub;
    float v = 0.f;
    if (i < N) v = A[(long long)i * HDIM + j] * w[j];
    for (int o = 32; o > 0; o >>= 1) v += __shfl_down(v, o);
    int wave = threadIdx.x >> 6;
    if ((threadIdx.x & 63) == 0) part[wave] = v;
    __syncthreads();
    if (threadIdx.x == 0) {
        int i0 = blockIdx.x * 2;
        if (i0 < N)     m3[i0]     = part[0] + part[1];
        if (i0 + 1 < N) m3[i0 + 1] = part[2] + part[3];
    }
}

__global__ void k_init_out(const float* m3, const float* dis, const float* b3,
                           float* outp, int N) {
    int i = blockIdx.x * blockDim.x + threadIdx.x;
    if (i < N) {
        float d = dis[i];
        outp[i] = m3[i] * d * d + b3[0];
    }
}

__global__ void k_scat_o(const float* m3, const void* ei, const int* flag,
                         const float* dis, float* outp, int E) {
    int e = blockIdx.x * blockDim.x + threadIdx.x;
    if (e < E) {
        int is64 = *flag;
        int s = eget(ei, e, is64);
        int d = eget(ei, (long long)E + e, is64);
        atomicAdd(&outp[d], m3[s] * dis[s] * dis[d]);
    }
}

__global__ void k_sigmoid(const float* outp, float* out, int N) {
    int i = blockIdx.x * blockDim.x + threadIdx.x;
    if (i < N) out[i] = 1.f / (1.f + expf(-outp[i]));
}

extern "C" void kernel_launch(void* const* d_in, const int* in_sizes, int n_in,
                              void* d_out, int out_size, void* d_ws, size_t ws_size,
                              hipStream_t stream) {
    const float* x  = (const float*)d_in[0];
    const void*  ei = d_in[1];
    const float* W1 = (const float*)d_in[2];
    const float* b1 = (const float*)d_in[3];
    const float* W2 = (const float*)d_in[4];
    const float* b2 = (const float*)d_in[5];
    const float* W3 = (const float*)d_in[6];
    const float* b3 = (const float*)d_in[7];
    const float* g1 = (const float*)d_in[8];
    const float* be1 = (const float*)d_in[9];
    const float* g2 = (const float*)d_in[10];
    const float* be2 = (const float*)d_in[11];

    const int N = in_sizes[0] / 6;
    const int E = in_sizes[1] / 2;
    const float invN = 1.0f / (float)N;

    // workspace layout (floats)
    float* ws = (float*)d_ws;
    int*   flag = (int*)ws;                 // [0..15] reserved
    float* dis  = ws + 16;                  // N  (deg then rsqrt in place)
    float* aggx = dis + N;                  // 6N
    float* m3   = aggx + (long long)6 * N;  // N
    float* outp = m3 + N;                   // N
    float* S1   = outp + N;                 // 256
    float* P1   = S1 + 256;                 // 256
    float* S2   = P1 + 256;                 // 256
    float* P2   = S2 + 256;                 // 256
    float* Hb1  = P2 + 256;                 // N*128
    float* Hb2  = Hb1 + (long long)N * HDIM;// N*128

    const int T = 256;
    const int bN   = (N + T - 1) / T;
    const int bE   = (E + T - 1) / T;
    const int b6N  = (6 * N + T - 1) / T;
    const int bNH  = (int)(((long long)N * HDIM + T - 1) / T);

    // --- norm precompute ---
    k_detect<<<1, 64, 0, stream>>>((const int*)ei, flag);
    k_fill<<<bN, T, 0, stream>>>(dis, 1.0f, N);                 // self-loop deg
    k_deg<<<bE, T, 0, stream>>>(ei, flag, dis, E);
    k_rsqrt_inplace<<<bN, T, 0, stream>>>(dis, N);

    // --- layer 1: aggregate x (6-wide), then GEMM 6->128, BN+ReLU ---
    k_init_aggx<<<b6N, T, 0, stream>>>(x, dis, aggx, N);
    k_scat_x<<<bE, T, 0, stream>>>(x, ei, flag, dis, aggx, E);
    k_gemm6<<<1024, T, 0, stream>>>(aggx, W1, b1, Hb1, N);
    k_fill<<<1, T, 0, stream>>>(S1, 0.0f, 256);
    k_colsum<<<512, T, 0, stream>>>(Hb1, N, S1);
    k_bnparams<<<1, 128, 0, stream>>>(S1, g1, be1, invN, P1);
    // h1 in place; Hb2 = h1 * dis^2 (self-loop init for layer-2 agg)
    k_bnrelu<<<bNH, T, 0, stream>>>(Hb1, P1, dis, Hb2, N);

    // --- layer 2: aggregate h1 (128-wide), GEMM 128x128, BN+ReLU ---
    k_scat_h<<<(E + 1) / 2, T, 0, stream>>>(Hb1, ei, flag, dis, Hb2, E);
    k_gemm128<<<2048, T, 0, stream>>>(Hb2, W2, b2, Hb1, N);
    k_fill<<<1, T, 0, stream>>>(S2, 0.0f, 256);
    k_colsum<<<512, T, 0, stream>>>(Hb1, N, S2);
    k_bnparams<<<1, 128, 0, stream>>>(S2, g2, be2, invN, P2);
    k_bnrelu<<<bNH, T, 0, stream>>>(Hb1, P2, dis, nullptr, N);  // h2 in place

    // --- layer 3: multiply first (128->1), then aggregate scalars ---
    k_gemv<<<(N + 1) / 2, T, 0, stream>>>(Hb1, W3, m3, N);
    k_init_out<<<bN, T, 0, stream>>>(m3, dis, b3, outp, N);
    k_scat_o<<<bE, T, 0, stream>>>(m3, ei, flag, dis, outp, E);
    k_sigmoid<<<bN, T, 0, stream>>>(outp, (float*)d_out, N);
}

// Round 2
// 611.131 us; speedup vs baseline: 1.8368x; 1.8368x over previous
//
#include <hip/hip_runtime.h>
#include <hip/hip_bf16.h>
#include <math.h>

#define HDIM 128
#define BN_EPS 1e-5f
#define CHUNK 512

// ---- edge index fetch: handles int32 or int64 on-device layout ----
__device__ __forceinline__ int eget(const void* ei, long long pos, int is64) {
    return is64 ? (int)((const long long*)ei)[pos] : ((const int*)ei)[pos];
}

// Detect int64 vs int32 layout: int64 values < 2^31 have zero hi-words.
__global__ void k_detect(const int* ei32, int* flag) {
    if (threadIdx.x == 0) {
        int nz = 0;
        for (int k = 0; k < 64; ++k) nz += (ei32[2 * k + 1] != 0);
        *flag = (nz < 8) ? 1 : 0;   // 1 => int64
    }
}

__global__ void k_zeroi(int* p, int n) {
    int t = blockIdx.x * blockDim.x + threadIdx.x;
    if (t < n) p[t] = 0;
}

__global__ void k_zerof(float* p, int n) {
    int t = blockIdx.x * blockDim.x + threadIdx.x;
    if (t < n) p[t] = 0.f;
}

// count in-degree (excluding self loops)
__global__ void k_count(const void* ei, const int* flag, int* cnt, int E) {
    int e = blockIdx.x * blockDim.x + threadIdx.x;
    if (e < E) {
        int d = eget(ei, (long long)E + e, *flag);
        atomicAdd(&cnt[d], 1);
    }
}

// dis[i] = rsqrt(cnt[i] + 1)   (+1 = self loop, so always > 0)
__global__ void k_dis(const int* cnt, float* dis, int N) {
    int i = blockIdx.x * blockDim.x + threadIdx.x;
    if (i < N) dis[i] = rsqrtf((float)(cnt[i] + 1));
}

// ---- 3-kernel exclusive scan of cnt[N] -> rowptr[N+1] ----
__global__ void k_scan1(const int* cnt, int* bsum, int N) {
    __shared__ int s[256];
    int t = threadIdx.x;
    int i = blockIdx.x * CHUNK + t;
    int v = 0;
    if (i < N) v += cnt[i];
    if (i + 256 < N && t + 256 < CHUNK) v += cnt[i + 256];
    s[t] = v; __syncthreads();
    for (int o = 128; o > 0; o >>= 1) {
        if (t < o) s[t] += s[t + o];
        __syncthreads();
    }
    if (t == 0) bsum[blockIdx.x] = s[0];
}

__global__ void k_scan2(int* bsum, int nb) {
    __shared__ int s[512];
    int t = threadIdx.x;
    int carry = 0;
    for (int base = 0; base < nb; base += 512) {
        int i = base + t;
        int v = (i < nb) ? bsum[i] : 0;
        s[t] = v; __syncthreads();
        for (int o = 1; o < 512; o <<= 1) {
            int add = (t >= o) ? s[t - o] : 0;
            __syncthreads();
            s[t] += add;
            __syncthreads();
        }
        if (i < nb) bsum[i] = carry + s[t] - v;   // exclusive
        carry += s[511];
        __syncthreads();
    }
}

__global__ void k_scan3(const int* cnt, const int* bsum, int* rowptr, int N) {
    __shared__ int s[CHUNK];
    int t = threadIdx.x;                       // blockDim == CHUNK
    int i = blockIdx.x * CHUNK + t;
    int v = (i < N) ? cnt[i] : 0;
    s[t] = v; __syncthreads();
    for (int o = 1; o < CHUNK; o <<= 1) {
        int add = (t >= o) ? s[t - o] : 0;
        __syncthreads();
        s[t] += add;
        __syncthreads();
    }
    if (i < N) rowptr[i] = bsum[blockIdx.x] + s[t] - v;
    if (i == N - 1) rowptr[N] = bsum[blockIdx.x] + s[t];
}

// place each edge into its dst bucket; enorm = dis[s]*dis[d]
__global__ void k_fillcsr(const void* ei, const int* flag, const float* dis,
                          const int* rowptr, int* fill, int* esrc, float* enorm, int E) {
    int e = blockIdx.x * blockDim.x + threadIdx.x;
    if (e < E) {
        int is64 = *flag;
        int s = eget(ei, e, is64);
        int d = eget(ei, (long long)E + e, is64);
        int pos = rowptr[d] + atomicAdd(&fill[d], 1);
        esrc[pos] = s;
        enorm[pos] = dis[s] * dis[d];
    }
}

// layer-1 aggregation of 6-wide x (thread per node, self loop fused)
__global__ void k_gath_x(const float* __restrict__ x, const int* __restrict__ rowptr,
                         const int* __restrict__ esrc, const float* __restrict__ enorm,
                         const float* __restrict__ dis, float* __restrict__ aggx, int N) {
    int i = blockIdx.x * blockDim.x + threadIdx.x;
    if (i < N) {
        float d = dis[i], d2 = d * d;
        float a0 = x[i * 6 + 0] * d2, a1 = x[i * 6 + 1] * d2, a2 = x[i * 6 + 2] * d2;
        float a3 = x[i * 6 + 3] * d2, a4 = x[i * 6 + 4] * d2, a5 = x[i * 6 + 5] * d2;
        int p0 = rowptr[i], p1 = rowptr[i + 1];
        for (int p = p0; p < p1; ++p) {
            int s = esrc[p];
            float nr = enorm[p];
            a0 += x[s * 6 + 0] * nr; a1 += x[s * 6 + 1] * nr; a2 += x[s * 6 + 2] * nr;
            a3 += x[s * 6 + 3] * nr; a4 += x[s * 6 + 4] * nr; a5 += x[s * 6 + 5] * nr;
        }
        aggx[i * 6 + 0] = a0; aggx[i * 6 + 1] = a1; aggx[i * 6 + 2] = a2;
        aggx[i * 6 + 3] = a3; aggx[i * 6 + 4] = a4; aggx[i * 6 + 5] = a5;
    }
}

// out[i][j] = sum_k aggx[i][k]*W1[k][j] + b1[j]   (K=6)
__global__ void k_gemm6(const float* __restrict__ aggx, const float* __restrict__ W1,
                        const float* __restrict__ b1, float* __restrict__ out, int N) {
    __shared__ float w[6 * HDIM];
    __shared__ float bb[HDIM];
    for (int t = threadIdx.x; t < 6 * HDIM; t += blockDim.x) w[t] = W1[t];
    if (threadIdx.x < HDIM) bb[threadIdx.x] = b1[threadIdx.x];
    __syncthreads();
    int j = threadIdx.x & (HDIM - 1);
    int sub = threadIdx.x >> 7;
    for (int i = blockIdx.x * 2 + sub; i < N; i += gridDim.x * 2) {
        const float* r = &aggx[i * 6];
        float acc = bb[j];
        acc += r[0] * w[0 * HDIM + j];
        acc += r[1] * w[1 * HDIM + j];
        acc += r[2] * w[2 * HDIM + j];
        acc += r[3] * w[3 * HDIM + j];
        acc += r[4] * w[4 * HDIM + j];
        acc += r[5] * w[5 * HDIM + j];
        out[(long long)i * HDIM + j] = acc;
    }
}

// per-column sum / sum-sq -> S[0:128]=sum, S[128:256]=sumsq
__global__ void k_colsum(const float* __restrict__ h, int N, float* __restrict__ S) {
    int j = threadIdx.x & (HDIM - 1);
    float s1 = 0.f, s2 = 0.f;
    int sub = threadIdx.x >> 7;
    for (int i = blockIdx.x * 2 + sub; i < N; i += gridDim.x * 2) {
        float v = h[(long long)i * HDIM + j];
        s1 += v; s2 += v * v;
    }
    __shared__ float sh1[256], sh2[256];
    sh1[threadIdx.x] = s1; sh2[threadIdx.x] = s2;
    __syncthreads();
    if (threadIdx.x < HDIM) {
        s1 = sh1[threadIdx.x] + sh1[threadIdx.x + HDIM];
        s2 = sh2[threadIdx.x] + sh2[threadIdx.x + HDIM];
        atomicAdd(&S[j], s1);
        atomicAdd(&S[HDIM + j], s2);
    }
}

// P[0:128]=alpha, P[128:256]=beta
__global__ void k_bnparams(const float* S, const float* g, const float* be,
                           float invN, float* P) {
    int j = threadIdx.x;
    if (j < HDIM) {
        float mu = S[j] * invN;
        float var = S[HDIM + j] * invN - mu * mu;
        float a = g[j] * rsqrtf(var + BN_EPS);
        P[j] = a;
        P[HDIM + j] = be[j] - mu * a;
    }
}

__global__ void k_bnrelu(float* h, const float* __restrict__ P, long long total) {
    long long t = (long long)blockIdx.x * blockDim.x + threadIdx.x;
    if (t < total) {
        int j = (int)(t & (HDIM - 1));
        h[t] = fmaxf(P[j] * h[t] + P[HDIM + j], 0.f);
    }
}

// layer-2 aggregation (gather): agg[i][j] = h[i][j]*dis^2 + sum_e h[src][j]*norm
__global__ void k_gath_h(const float* __restrict__ hsrc, const int* __restrict__ rowptr,
                         const int* __restrict__ esrc, const float* __restrict__ enorm,
                         const float* __restrict__ dis, float* __restrict__ agg, int N) {
    int i = blockIdx.x * 2 + (threadIdx.x >> 7);
    int j = threadIdx.x & (HDIM - 1);
    if (i < N) {
        float d = dis[i];
        float acc = hsrc[(long long)i * HDIM + j] * d * d;
        int p0 = rowptr[i], p1 = rowptr[i + 1];
        for (int p = p0; p < p1; ++p) {
            int s = esrc[p];
            float nr = enorm[p];
            acc += hsrc[(long long)s * HDIM + j] * nr;
        }
        agg[(long long)i * HDIM + j] = acc;
    }
}

// out[i][j] = sum_k A[i][k]*W[k][j] + b[j]  (K=128); 4 rows/thread, W in LDS
__global__ __launch_bounds__(1024, 8)
void k_gemm128(const float* __restrict__ A, const float* __restrict__ W,
               const float* __restrict__ b, float* __restrict__ out, int N) {
    __shared__ float w[HDIM * HDIM];
    for (int t = threadIdx.x; t < HDIM * HDIM; t += 1024) w[t] = W[t];
    __syncthreads();
    const int j = threadIdx.x & (HDIM - 1);
    const int sub = threadIdx.x >> 7;          // 0..7
    const float bj = b[j];
    for (long long base = (long long)blockIdx.x * 32 + sub * 4; base < N;
         base += (long long)gridDim.x * 32) {
        if (base + 4 <= N) {
            const float* __restrict__ r = A + base * HDIM;
            float a0 = bj, a1 = bj, a2 = bj, a3 = bj;
            #pragma unroll 4
            for (int k = 0; k < HDIM; k += 4) {
                const float4 v0 = *(const float4*)(r + 0 * HDIM + k);
                const float4 v1 = *(const float4*)(r + 1 * HDIM + k);
                const float4 v2 = *(const float4*)(r + 2 * HDIM + k);
                const float4 v3 = *(const float4*)(r + 3 * HDIM + k);
                const float w0 = w[(k + 0) * HDIM + j];
                const float w1 = w[(k + 1) * HDIM + j];
                const float w2 = w[(k + 2) * HDIM + j];
                const float w3 = w[(k + 3) * HDIM + j];
                a0 = fmaf(v0.x, w0, a0); a1 = fmaf(v1.x, w0, a1);
                a2 = fmaf(v2.x, w0, a2); a3 = fmaf(v3.x, w0, a3);
                a0 = fmaf(v0.y, w1, a0); a1 = fmaf(v1.y, w1, a1);
                a2 = fmaf(v2.y, w1, a2); a3 = fmaf(v3.y, w1, a3);
                a0 = fmaf(v0.z, w2, a0); a1 = fmaf(v1.z, w2, a1);
                a2 = fmaf(v2.z, w2, a2); a3 = fmaf(v3.z, w2, a3);
                a0 = fmaf(v0.w, w3, a0); a1 = fmaf(v1.w, w3, a1);
                a2 = fmaf(v2.w, w3, a2); a3 = fmaf(v3.w, w3, a3);
            }
            out[(base + 0) * HDIM + j] = a0;
            out[(base + 1) * HDIM + j] = a1;
            out[(base + 2) * HDIM + j] = a2;
            out[(base + 3) * HDIM + j] = a3;
        } else {
            for (long long i = base; i < N; ++i) {
                float acc = bj;
                for (int k = 0; k < HDIM; ++k)
                    acc = fmaf(A[i * HDIM + k], w[k * HDIM + j], acc);
                out[i * HDIM + j] = acc;
            }
        }
    }
}

// m3[i] = dot(h2[i], W3); block handles 2 rows
__global__ void k_gemv(const float* __restrict__ A, const float* __restrict__ W3,
                       float* __restrict__ m3, int N) {
    __shared__ float w[HDIM];
    __shared__ float part[4];
    if (threadIdx.x < HDIM) w[threadIdx.x] = W3[threadIdx.x];
    __syncthreads();
    int sub = threadIdx.x >> 7;
    int j = threadIdx.x & (HDIM - 1);
    int i = blockIdx.x * 2 + sub;
    float v = 0.f;
    if (i < N) v = A[(long long)i * HDIM + j] * w[j];
    for (int o = 32; o > 0; o >>= 1) v += __shfl_down(v, o);
    int wave = threadIdx.x >> 6;
    if ((threadIdx.x & 63) == 0) part[wave] = v;
    __syncthreads();
    if (threadIdx.x == 0) {
        int i0 = blockIdx.x * 2;
        if (i0 < N)     m3[i0]     = part[0] + part[1];
        if (i0 + 1 < N) m3[i0 + 1] = part[2] + part[3];
    }
}

// layer-3 gather + bias + sigmoid, writes final output
__global__ void k_gath_o(const float* __restrict__ m3, const int* __restrict__ rowptr,
                         const int* __restrict__ esrc, const float* __restrict__ enorm,
                         const float* __restrict__ dis, const float* __restrict__ b3,
                         float* __restrict__ out, int N) {
    int i = blockIdx.x * blockDim.x + threadIdx.x;
    if (i < N) {
        float d = dis[i];
        float acc = m3[i] * d * d;
        int p0 = rowptr[i], p1 = rowptr[i + 1];
        for (int p = p0; p < p1; ++p)
            acc += m3[esrc[p]] * enorm[p];
        acc += b3[0];
        out[i] = 1.f / (1.f + expf(-acc));
    }
}

extern "C" void kernel_launch(void* const* d_in, const int* in_sizes, int n_in,
                              void* d_out, int out_size, void* d_ws, size_t ws_size,
                              hipStream_t stream) {
    const float* x  = (const float*)d_in[0];
    const void*  ei = d_in[1];
    const float* W1 = (const float*)d_in[2];
    const float* b1 = (const float*)d_in[3];
    const float* W2 = (const float*)d_in[4];
    const float* b2 = (const float*)d_in[5];
    const float* W3 = (const float*)d_in[6];
    const float* b3 = (const float*)d_in[7];
    const float* g1 = (const float*)d_in[8];
    const float* be1 = (const float*)d_in[9];
    const float* g2 = (const float*)d_in[10];
    const float* be2 = (const float*)d_in[11];

    const int N = in_sizes[0] / 6;
    const int E = in_sizes[1] / 2;
    const float invN = 1.0f / (float)N;

    // ---- workspace layout (float units) ----
    float* ws = (float*)d_ws;
    long long off = 0;
    int*   flag   = (int*)ws;                 off += 16;
    float* dis    = ws + off;                 off += N;
    int*   cnt    = (int*)(ws + off);         off += N;        // reused as fill
    int*   rowptr = (int*)(ws + off);         off += N + 16;
    int*   esrc   = (int*)(ws + off);         off += E;
    float* enorm  = ws + off;                 off += E;
    int*   bsum   = (int*)(ws + off);         off += 512;
    float* S1     = ws + off;                 off += 256;
    float* P1     = ws + off;                 off += 256;
    float* S2     = ws + off;                 off += 256;
    float* P2     = ws + off;                 off += 256;
    float* aggx   = ws + off;                 off += (long long)6 * N;
    float* m3     = ws + off;                 off += N;
    float* Hb1    = ws + off;                 off += (long long)HDIM * N;
    float* Hb2    = ws + off;                 off += (long long)HDIM * N;

    const int T = 256;
    const int bN  = (N + T - 1) / T;
    const int bE  = (E + T - 1) / T;
    const int bNH = (int)(((long long)N * HDIM + T - 1) / T);
    const int nchunk = (N + CHUNK - 1) / CHUNK;

    // ---- CSR build ----
    k_detect<<<1, 64, 0, stream>>>((const int*)ei, flag);
    k_zeroi<<<bN, T, 0, stream>>>(cnt, N);
    k_count<<<bE, T, 0, stream>>>(ei, flag, cnt, E);
    k_dis<<<bN, T, 0, stream>>>(cnt, dis, N);
    k_scan1<<<nchunk, 256, 0, stream>>>(cnt, bsum, N);
    k_scan2<<<1, 512, 0, stream>>>(bsum, nchunk);
    k_scan3<<<nchunk, CHUNK, 0, stream>>>(cnt, bsum, rowptr, N);
    k_zeroi<<<bN, T, 0, stream>>>(cnt, N);    // cnt becomes fill
    k_fillcsr<<<bE, T, 0, stream>>>(ei, flag, dis, rowptr, cnt, esrc, enorm, E);

    // ---- layer 1: gather x (6-wide) -> GEMM 6->128 -> BN+ReLU ----
    k_gath_x<<<bN, T, 0, stream>>>(x, rowptr, esrc, enorm, dis, aggx, N);
    k_gemm6<<<1024, T, 0, stream>>>(aggx, W1, b1, Hb1, N);
    k_zerof<<<1, T, 0, stream>>>(S1, 256);
    k_colsum<<<512, T, 0, stream>>>(Hb1, N, S1);
    k_bnparams<<<1, 128, 0, stream>>>(S1, g1, be1, invN, P1);
    k_bnrelu<<<bNH, T, 0, stream>>>(Hb1, P1, (long long)N * HDIM);

    // ---- layer 2: gather h1 (128-wide) -> GEMM 128x128 -> BN+ReLU ----
    k_gath_h<<<(N + 1) / 2, T, 0, stream>>>(Hb1, rowptr, esrc, enorm, dis, Hb2, N);
    k_gemm128<<<512, 1024, 0, stream>>>(Hb2, W2, b2, Hb1, N);
    k_zerof<<<1, T, 0, stream>>>(S2, 256);
    k_colsum<<<512, T, 0, stream>>>(Hb1, N, S2);
    k_bnparams<<<1, 128, 0, stream>>>(S2, g2, be2, invN, P2);
    k_bnrelu<<<bNH, T, 0, stream>>>(Hb1, P2, (long long)N * HDIM);

    // ---- layer 3: 128->1 then gather scalars + sigmoid ----
    k_gemv<<<(N + 1) / 2, T, 0, stream>>>(Hb1, W3, m3, N);
    k_gath_o<<<bN, T, 0, stream>>>(m3, rowptr, esrc, enorm, dis, b3, (float*)d_out, N);
}

// Round 3
// 294.290 us; speedup vs baseline: 3.8144x; 2.0766x over previous
//
#include <hip/hip_runtime.h>
#include <hip/hip_bf16.h>
#include <math.h>

#define HDIM 128
#define BN_EPS 1e-5f
#define CHUNK 512
#define TM 64   // rows per layer-2 tile

// ---- edge index fetch: handles int32 or int64 on-device layout ----
__device__ __forceinline__ int eget(const void* ei, long long pos, int is64) {
    return is64 ? (int)((const long long*)ei)[pos] : ((const int*)ei)[pos];
}

// Detect int64 vs int32 layout: int64 values < 2^31 have zero hi-words.
__global__ void k_detect(const int* ei32, int* flag) {
    if (threadIdx.x == 0) {
        int nz = 0;
        for (int k = 0; k < 64; ++k) nz += (ei32[2 * k + 1] != 0);
        *flag = (nz < 8) ? 1 : 0;   // 1 => int64
    }
}

// count in-degree (excluding self loops)
__global__ void k_count(const void* ei, const int* flag, int* cnt, int E) {
    int e = blockIdx.x * blockDim.x + threadIdx.x;
    if (e < E) {
        int d = eget(ei, (long long)E + e, *flag);
        atomicAdd(&cnt[d], 1);
    }
}

// dis[i] = rsqrt(cnt[i] + 1)   (+1 = self loop, so always > 0)
__global__ void k_dis(const int* cnt, float* dis, int N) {
    int i = blockIdx.x * blockDim.x + threadIdx.x;
    if (i < N) dis[i] = rsqrtf((float)(cnt[i] + 1));
}

// ---- 3-kernel exclusive scan of cnt[N] -> rowptr[N+1] ----
__global__ void k_scan1(const int* cnt, int* bsum, int N) {
    __shared__ int s[256];
    int t = threadIdx.x;
    int i = blockIdx.x * CHUNK + t;
    int v = 0;
    if (i < N) v += cnt[i];
    if (i + 256 < N && t + 256 < CHUNK) v += cnt[i + 256];
    s[t] = v; __syncthreads();
    for (int o = 128; o > 0; o >>= 1) {
        if (t < o) s[t] += s[t + o];
        __syncthreads();
    }
    if (t == 0) bsum[blockIdx.x] = s[0];
}

__global__ void k_scan2(int* bsum, int nb) {
    __shared__ int s[512];
    int t = threadIdx.x;
    int carry = 0;
    for (int base = 0; base < nb; base += 512) {
        int i = base + t;
        int v = (i < nb) ? bsum[i] : 0;
        s[t] = v; __syncthreads();
        for (int o = 1; o < 512; o <<= 1) {
            int add = (t >= o) ? s[t - o] : 0;
            __syncthreads();
            s[t] += add;
            __syncthreads();
        }
        if (i < nb) bsum[i] = carry + s[t] - v;   // exclusive
        carry += s[511];
        __syncthreads();
    }
}

__global__ void k_scan3(const int* cnt, const int* bsum, int* rowptr, int N) {
    __shared__ int s[CHUNK];
    int t = threadIdx.x;                       // blockDim == CHUNK
    int i = blockIdx.x * CHUNK + t;
    int v = (i < N) ? cnt[i] : 0;
    s[t] = v; __syncthreads();
    for (int o = 1; o < CHUNK; o <<= 1) {
        int add = (t >= o) ? s[t - o] : 0;
        __syncthreads();
        s[t] += add;
        __syncthreads();
    }
    if (i < N) rowptr[i] = bsum[blockIdx.x] + s[t] - v;
    if (i == N - 1) rowptr[N] = bsum[blockIdx.x] + s[t];
}

// place each edge into its dst bucket; enorm = dis[s]*dis[d]
__global__ void k_fillcsr(const void* ei, const int* flag, const float* dis,
                          const int* rowptr, int* fill, int* esrc, float* enorm, int E) {
    int e = blockIdx.x * blockDim.x + threadIdx.x;
    if (e < E) {
        int is64 = *flag;
        int s = eget(ei, e, is64);
        int d = eget(ei, (long long)E + e, is64);
        int pos = rowptr[d] + atomicAdd(&fill[d], 1);
        esrc[pos] = s;
        enorm[pos] = dis[s] * dis[d];
    }
}

// layer-1 aggregation of 6-wide x (thread per node, self loop fused)
__global__ void k_gath_x(const float* __restrict__ x, const int* __restrict__ rowptr,
                         const int* __restrict__ esrc, const float* __restrict__ enorm,
                         const float* __restrict__ dis, float* __restrict__ aggx, int N) {
    int i = blockIdx.x * blockDim.x + threadIdx.x;
    if (i < N) {
        float d = dis[i], d2 = d * d;
        float a0 = x[i * 6 + 0] * d2, a1 = x[i * 6 + 1] * d2, a2 = x[i * 6 + 2] * d2;
        float a3 = x[i * 6 + 3] * d2, a4 = x[i * 6 + 4] * d2, a5 = x[i * 6 + 5] * d2;
        int p0 = rowptr[i], p1 = rowptr[i + 1];
        for (int p = p0; p < p1; ++p) {
            int s = esrc[p];
            float nr = enorm[p];
            a0 += x[s * 6 + 0] * nr; a1 += x[s * 6 + 1] * nr; a2 += x[s * 6 + 2] * nr;
            a3 += x[s * 6 + 3] * nr; a4 += x[s * 6 + 4] * nr; a5 += x[s * 6 + 5] * nr;
        }
        aggx[i * 6 + 0] = a0; aggx[i * 6 + 1] = a1; aggx[i * 6 + 2] = a2;
        aggx[i * 6 + 3] = a3; aggx[i * 6 + 4] = a4; aggx[i * 6 + 5] = a5;
    }
}

// out[i][j] = sum_k aggx[i][k]*W1[k][j] + b1[j]  (K=6), fused column sums
__global__ void k_gemm6(const float* __restrict__ aggx, const float* __restrict__ W1,
                        const float* __restrict__ b1, float* __restrict__ out,
                        float* __restrict__ S, int N) {
    __shared__ float w[6 * HDIM];
    __shared__ float bb[HDIM];
    __shared__ float sh1[256], sh2[256];
    for (int t = threadIdx.x; t < 6 * HDIM; t += blockDim.x) w[t] = W1[t];
    if (threadIdx.x < HDIM) bb[threadIdx.x] = b1[threadIdx.x];
    __syncthreads();
    int j = threadIdx.x & (HDIM - 1);
    int sub = threadIdx.x >> 7;
    float s1 = 0.f, s2 = 0.f;
    for (long long i = blockIdx.x * 2 + sub; i < N; i += (long long)gridDim.x * 2) {
        const float* r = &aggx[i * 6];
        float acc = bb[j];
        acc += r[0] * w[0 * HDIM + j];
        acc += r[1] * w[1 * HDIM + j];
        acc += r[2] * w[2 * HDIM + j];
        acc += r[3] * w[3 * HDIM + j];
        acc += r[4] * w[4 * HDIM + j];
        acc += r[5] * w[5 * HDIM + j];
        out[i * HDIM + j] = acc;
        s1 += acc; s2 += acc * acc;
    }
    sh1[threadIdx.x] = s1; sh2[threadIdx.x] = s2;
    __syncthreads();
    if (threadIdx.x < HDIM) {
        atomicAdd(&S[j], sh1[j] + sh1[j + HDIM]);
        atomicAdd(&S[HDIM + j], sh2[j] + sh2[j + HDIM]);
    }
}

// P[0:128]=alpha, P[128:256]=beta
__global__ void k_bnparams(const float* S, const float* g, const float* be,
                           float invN, float* P) {
    int j = threadIdx.x;
    if (j < HDIM) {
        float mu = S[j] * invN;
        float var = S[HDIM + j] * invN - mu * mu;
        float a = g[j] * rsqrtf(var + BN_EPS);
        P[j] = a;
        P[HDIM + j] = be[j] - mu * a;
    }
}

// ===== fused layer 2: gather(h1, BN1+ReLU on the fly) -> LDS tile ->
//       GEMM 128x128 (W2 from L2) -> out + column-sum partial epilogue =====
__global__ __launch_bounds__(512, 4)
void k_agg_gemm(const float* __restrict__ h1,   // raw m1 (pre-BN), N x 128
                const float* __restrict__ P1,
                const int* __restrict__ rowptr, const int* __restrict__ esrc,
                const float* __restrict__ enorm, const float* __restrict__ dis,
                const float* __restrict__ W, const float* __restrict__ b,
                float* __restrict__ out,        // m2 raw, N x 128
                float* __restrict__ S,          // 256 col sums (atomic)
                int N) {
    __shared__ float At[TM * HDIM];             // 32 KB
    const int tid = threadIdx.x;
    const long long i0 = (long long)blockIdx.x * TM;

    // ---- gather phase: 16 node-groups, 32 lanes x float4 each ----
    {
        const int l = tid & 31;
        const int q = tid >> 5;                 // 0..15
        const int c4 = l * 4;
        const float4 pa = *(const float4*)&P1[c4];
        const float4 pb = *(const float4*)&P1[HDIM + c4];
        for (int nn = q; nn < TM; nn += 16) {
            long long i = i0 + nn;
            float4 acc = make_float4(0.f, 0.f, 0.f, 0.f);
            if (i < N) {
                float d = dis[i], d2 = d * d;
                float4 v = *(const float4*)&h1[i * HDIM + c4];
                acc.x = fmaxf(fmaf(pa.x, v.x, pb.x), 0.f) * d2;
                acc.y = fmaxf(fmaf(pa.y, v.y, pb.y), 0.f) * d2;
                acc.z = fmaxf(fmaf(pa.z, v.z, pb.z), 0.f) * d2;
                acc.w = fmaxf(fmaf(pa.w, v.w, pb.w), 0.f) * d2;
                int p0 = rowptr[i], p1e = rowptr[i + 1];
                for (int p = p0; p < p1e; ++p) {
                    int s = esrc[p];
                    float nr = enorm[p];
                    float4 u = *(const float4*)&h1[(long long)s * HDIM + c4];
                    acc.x += fmaxf(fmaf(pa.x, u.x, pb.x), 0.f) * nr;
                    acc.y += fmaxf(fmaf(pa.y, u.y, pb.y), 0.f) * nr;
                    acc.z += fmaxf(fmaf(pa.z, u.z, pb.z), 0.f) * nr;
                    acc.w += fmaxf(fmaf(pa.w, u.w, pb.w), 0.f) * nr;
                }
            }
            *(float4*)&At[nn * HDIM + c4] = acc;
        }
    }
    __syncthreads();

    // ---- GEMM phase: thread = (row group rg, col group cg), 4x4 block ----
    const int cg = tid & 31;
    const int rg = tid >> 5;                    // 0..15
    const int c0 = cg * 4;
    const int r0 = rg * 4;
    float acc[4][4];
    {
        const float4 bv = *(const float4*)&b[c0];
        #pragma unroll
        for (int rr = 0; rr < 4; ++rr) {
            acc[rr][0] = bv.x; acc[rr][1] = bv.y; acc[rr][2] = bv.z; acc[rr][3] = bv.w;
        }
    }
    for (int k = 0; k < HDIM; k += 4) {
        const float4 w0 = *(const float4*)&W[(k + 0) * HDIM + c0];
        const float4 w1 = *(const float4*)&W[(k + 1) * HDIM + c0];
        const float4 w2 = *(const float4*)&W[(k + 2) * HDIM + c0];
        const float4 w3 = *(const float4*)&W[(k + 3) * HDIM + c0];
        #pragma unroll
        for (int rr = 0; rr < 4; ++rr) {
            const float4 av = *(const float4*)&At[(r0 + rr) * HDIM + k];
            acc[rr][0] = fmaf(av.x, w0.x, acc[rr][0]);
            acc[rr][1] = fmaf(av.x, w0.y, acc[rr][1]);
            acc[rr][2] = fmaf(av.x, w0.z, acc[rr][2]);
            acc[rr][3] = fmaf(av.x, w0.w, acc[rr][3]);
            acc[rr][0] = fmaf(av.y, w1.x, acc[rr][0]);
            acc[rr][1] = fmaf(av.y, w1.y, acc[rr][1]);
            acc[rr][2] = fmaf(av.y, w1.z, acc[rr][2]);
            acc[rr][3] = fmaf(av.y, w1.w, acc[rr][3]);
            acc[rr][0] = fmaf(av.z, w2.x, acc[rr][0]);
            acc[rr][1] = fmaf(av.z, w2.y, acc[rr][1]);
            acc[rr][2] = fmaf(av.z, w2.z, acc[rr][2]);
            acc[rr][3] = fmaf(av.z, w2.w, acc[rr][3]);
            acc[rr][0] = fmaf(av.w, w3.x, acc[rr][0]);
            acc[rr][1] = fmaf(av.w, w3.y, acc[rr][1]);
            acc[rr][2] = fmaf(av.w, w3.z, acc[rr][2]);
            acc[rr][3] = fmaf(av.w, w3.w, acc[rr][3]);
        }
    }

    // store + per-thread column partials (rows < N only)
    float cs1[4] = {0.f, 0.f, 0.f, 0.f};
    float cs2[4] = {0.f, 0.f, 0.f, 0.f};
    #pragma unroll
    for (int rr = 0; rr < 4; ++rr) {
        long long i = i0 + r0 + rr;
        if (i < N) {
            float4 o = make_float4(acc[rr][0], acc[rr][1], acc[rr][2], acc[rr][3]);
            *(float4*)&out[i * HDIM + c0] = o;
            #pragma unroll
            for (int cc = 0; cc < 4; ++cc) {
                float v = acc[rr][cc];
                cs1[cc] += v; cs2[cc] += v * v;
            }
        }
    }

    // reduce partials across 16 row-groups via LDS (reuse At), then atomics
    __syncthreads();
    #pragma unroll
    for (int cc = 0; cc < 4; ++cc) {
        At[rg * HDIM + c0 + cc]        = cs1[cc];
        At[2048 + rg * HDIM + c0 + cc] = cs2[cc];
    }
    __syncthreads();
    if (tid < 256) {
        int j = tid & (HDIM - 1);
        int which = tid >> 7;                   // 0 = sum, 1 = sumsq
        const float* bp = &At[which * 2048 + j];
        float s = 0.f;
        #pragma unroll
        for (int g = 0; g < 16; ++g) s += bp[g * HDIM];
        atomicAdd(&S[which * HDIM + j], s);
    }
}

// m3[i] = dot(relu(BN2(m2[i])), W3); 32 lanes x float4 per row, 8 rows/block
__global__ void k_gemv2(const float* __restrict__ A, const float* __restrict__ P,
                        const float* __restrict__ W3, float* __restrict__ m3, int N) {
    int l = threadIdx.x & 31;
    int row = blockIdx.x * 8 + (threadIdx.x >> 5);
    if (row < N) {
        int c4 = l * 4;
        float4 pa = *(const float4*)&P[c4];
        float4 pb = *(const float4*)&P[HDIM + c4];
        float4 w  = *(const float4*)&W3[c4];
        float4 v  = *(const float4*)&A[(long long)row * HDIM + c4];
        float s = fmaxf(fmaf(pa.x, v.x, pb.x), 0.f) * w.x
                + fmaxf(fmaf(pa.y, v.y, pb.y), 0.f) * w.y
                + fmaxf(fmaf(pa.z, v.z, pb.z), 0.f) * w.z
                + fmaxf(fmaf(pa.w, v.w, pb.w), 0.f) * w.w;
        for (int o = 16; o > 0; o >>= 1) s += __shfl_down(s, o, 32);
        if (l == 0) m3[row] = s;
    }
}

// layer-3 gather + bias + sigmoid, writes final output
__global__ void k_gath_o(const float* __restrict__ m3, const int* __restrict__ rowptr,
                         const int* __restrict__ esrc, const float* __restrict__ enorm,
                         const float* __restrict__ dis, const float* __restrict__ b3,
                         float* __restrict__ out, int N) {
    int i = blockIdx.x * blockDim.x + threadIdx.x;
    if (i < N) {
        float d = dis[i];
        float acc = m3[i] * d * d;
        int p0 = rowptr[i], p1 = rowptr[i + 1];
        for (int p = p0; p < p1; ++p)
            acc += m3[esrc[p]] * enorm[p];
        acc += b3[0];
        out[i] = 1.f / (1.f + expf(-acc));
    }
}

extern "C" void kernel_launch(void* const* d_in, const int* in_sizes, int n_in,
                              void* d_out, int out_size, void* d_ws, size_t ws_size,
                              hipStream_t stream) {
    const float* x  = (const float*)d_in[0];
    const void*  ei = d_in[1];
    const float* W1 = (const float*)d_in[2];
    const float* b1 = (const float*)d_in[3];
    const float* W2 = (const float*)d_in[4];
    const float* b2 = (const float*)d_in[5];
    const float* W3 = (const float*)d_in[6];
    const float* b3 = (const float*)d_in[7];
    const float* g1 = (const float*)d_in[8];
    const float* be1 = (const float*)d_in[9];
    const float* g2 = (const float*)d_in[10];
    const float* be2 = (const float*)d_in[11];

    const int N = in_sizes[0] / 6;
    const int E = in_sizes[1] / 2;
    const float invN = 1.0f / (float)N;

    // ---- workspace layout (float units) ----
    float* ws = (float*)d_ws;
    long long off = 0;
    int*   flag   = (int*)ws;                 off += 16;
    float* dis    = ws + off;                 off += N;
    int*   cnt    = (int*)(ws + off);         off += N;        // reused as fill
    int*   rowptr = (int*)(ws + off);         off += N + 16;
    int*   esrc   = (int*)(ws + off);         off += E;
    float* enorm  = ws + off;                 off += E;
    int*   bsum   = (int*)(ws + off);         off += 512;
    float* S1     = ws + off;                 off += 256;      // S2 adjacent
    float* S2     = ws + off;                 off += 256;
    float* P1     = ws + off;                 off += 256;
    float* P2     = ws + off;                 off += 256;
    float* aggx   = ws + off;                 off += (long long)6 * N;
    float* m3     = ws + off;                 off += N;
    float* Hb1    = ws + off;                 off += (long long)HDIM * N;
    float* Hb2    = ws + off;                 off += (long long)HDIM * N;

    const int T = 256;
    const int bN  = (N + T - 1) / T;
    const int bE  = (E + T - 1) / T;
    const int nchunk = (N + CHUNK - 1) / CHUNK;
    const int ntile  = (N + TM - 1) / TM;

    // ---- CSR build + norm ----
    hipMemsetAsync(S1, 0, 512 * sizeof(float), stream);   // S1 + S2
    k_detect<<<1, 64, 0, stream>>>((const int*)ei, flag);
    hipMemsetAsync(cnt, 0, (size_t)N * sizeof(int), stream);
    k_count<<<bE, T, 0, stream>>>(ei, flag, cnt, E);
    k_dis<<<bN, T, 0, stream>>>(cnt, dis, N);
    k_scan1<<<nchunk, 256, 0, stream>>>(cnt, bsum, N);
    k_scan2<<<1, 512, 0, stream>>>(bsum, nchunk);
    k_scan3<<<nchunk, CHUNK, 0, stream>>>(cnt, bsum, rowptr, N);
    hipMemsetAsync(cnt, 0, (size_t)N * sizeof(int), stream);   // becomes fill
    k_fillcsr<<<bE, T, 0, stream>>>(ei, flag, dis, rowptr, cnt, esrc, enorm, E);

    // ---- layer 1: gather x -> GEMM 6->128 (+colsum) -> BN params ----
    k_gath_x<<<bN, T, 0, stream>>>(x, rowptr, esrc, enorm, dis, aggx, N);
    k_gemm6<<<512, T, 0, stream>>>(aggx, W1, b1, Hb1, S1, N);
    k_bnparams<<<1, 128, 0, stream>>>(S1, g1, be1, invN, P1);

    // ---- layer 2 fused: gather(BN1+ReLU) -> GEMM (+colsum) ----
    k_agg_gemm<<<ntile, 512, 0, stream>>>(Hb1, P1, rowptr, esrc, enorm, dis,
                                          W2, b2, Hb2, S2, N);
    k_bnparams<<<1, 128, 0, stream>>>(S2, g2, be2, invN, P2);

    // ---- layer 3: (BN2+ReLU fused) 128->1, gather scalars + sigmoid ----
    k_gemv2<<<(N + 7) / 8, T, 0, stream>>>(Hb2, P2, W3, m3, N);
    k_gath_o<<<bN, T, 0, stream>>>(m3, rowptr, esrc, enorm, dis, b3, (float*)d_out, N);
}